// Round 7
// baseline (136.743 us; speedup 1.0000x reference)
//
#include <hip/hip_runtime.h>
#include <hip/hip_bf16.h>

typedef __attribute__((ext_vector_type(4)))  float f4;
typedef __attribute__((ext_vector_type(16))) float f32x16;
typedef __attribute__((ext_vector_type(8)))  short bf8;

__device__ __forceinline__ short f2bf(float f) {
    unsigned u = __builtin_bit_cast(unsigned, f);
    u += 0x7fff + ((u >> 16) & 1);          // round-to-nearest-even
    return (short)(u >> 16);
}

// ---------------------------------------------------------------------------
// Prep: fused B-matrix [256][128] packed as 32x32x16 MFMA B-fragments.
//   Bmat[k][n] = k<128 ? U_w[n][k]
//                      : A_w[n][k-128]*dw[k-128]/dw[n] + (n==k-128)*(0.05-rs[n])
// Frag f = kt*4+nt (kt=0..15 K-steps of 16, nt=0..3 col-tiles of 32):
//   pre[(f*64 + lane)*8 + j] = Bmat[kt*16 + (lane>>5)*8 + j][nt*32 + (lane&31)]
// (A is packed with the identical k-mapping, so any within-k-step permutation
//  error cancels; only the HW-verified C/D layout must be exact.)
// ---------------------------------------------------------------------------
__global__ void nemon_prep(const float* __restrict__ Uw,
                           const float* __restrict__ Aw,
                           const float* __restrict__ dvec,
                           short* __restrict__ pre)
{
    __shared__ float rs[128], dwv[128];
    const int tid = threadIdx.x;
    if (tid < 128) {
        float s = 0.f;
        #pragma unroll 8
        for (int k = 0; k < 128; ++k) s += fabsf(Aw[tid * 128 + k]);
        rs[tid]  = s;
        dwv[tid] = expf(dvec[tid]);
    }
    __syncthreads();
    for (int e = tid; e < 32768; e += 256) {
        const int j    = e & 7;
        const int lane = (e >> 3) & 63;
        const int f    = e >> 9;          // 0..63
        const int nt   = f & 3;
        const int kt   = f >> 2;          // 0..15
        const int k    = kt * 16 + (lane >> 5) * 8 + j;
        const int n    = nt * 32 + (lane & 31);
        float v;
        if (k < 128) {
            v = Uw[n * 128 + k];
        } else {
            const int k2 = k - 128;
            v = Aw[n * 128 + k2] * (dwv[k2] / dwv[n]);
            if (n == k2) v += 0.05f - rs[n];
        }
        pre[e] = f2bf(v);
    }
}

// ---------------------------------------------------------------------------
// Main v6: barrier-free streaming. 512 threads = 8 waves; each wave owns one
// 32-row tile end-to-end (loads -> cvt -> 64 MFMA -> dense stores). Weights
// in 64 KB LDS (staged once, ONE barrier). 2 blocks/CU, 16 waves/CU.
// All global loads 16B contiguous/lane; stores are 2x128B dense segments
// per instruction (full lines, no amplification). All LDS access linear.
// ---------------------------------------------------------------------------
__global__ __launch_bounds__(512, 4) void nemon_main(
    const float* __restrict__ x,
    const float* __restrict__ z,
    const float* __restrict__ Ub,
    const short* __restrict__ pre,
    float* __restrict__ out)
{
    __shared__ short W[32768];            // 64 KB B-fragments
    const int tid = threadIdx.x;

    {   // stage weights, linear (conflict-free)
        const int4* src = (const int4*)pre;
        int4*       dst = (int4*)W;
        #pragma unroll
        for (int i = 0; i < 8; ++i) dst[tid + 512 * i] = src[tid + 512 * i];
    }
    __syncthreads();                      // the only barrier

    const int wave = tid >> 6;
    const int lane = tid & 63;
    const int lo   = lane & 31;           // A row / C col (within tiles)
    const int hi   = lane >> 5;           // k-half selector

    const long tile = (long)blockIdx.x * 8 + wave;
    const long R    = tile * 32;          // first batch row of this wave

    // bias -> accumulator init (col = nt*32 + lo, same for all 16 regs)
    f32x16 acc[4];
    #pragma unroll
    for (int nt = 0; nt < 4; ++nt) {
        const float b = Ub[nt * 32 + lo];
        #pragma unroll
        for (int r = 0; r < 16; ++r) acc[nt][r] = b;
    }

    const float* xr = x + (R + lo) * 128 + hi * 8;
    const float* zr = z + (R + lo) * 128 + hi * 8;

    // K-steps 0..7 from x
    #pragma unroll
    for (int kt = 0; kt < 8; ++kt) {
        f4 a0 = *(const f4*)(xr + kt * 16);
        f4 a1 = *(const f4*)(xr + kt * 16 + 4);
        bf8 a = { f2bf(a0[0]), f2bf(a0[1]), f2bf(a0[2]), f2bf(a0[3]),
                  f2bf(a1[0]), f2bf(a1[1]), f2bf(a1[2]), f2bf(a1[3]) };
        #pragma unroll
        for (int nt = 0; nt < 4; ++nt) {
            bf8 b = *(const bf8*)&W[((kt * 4 + nt) * 64 + lane) * 8];
            acc[nt] = __builtin_amdgcn_mfma_f32_32x32x16_bf16(a, b, acc[nt], 0, 0, 0);
        }
    }
    // K-steps 8..15 from z
    #pragma unroll
    for (int kt = 8; kt < 16; ++kt) {
        f4 a0 = *(const f4*)(zr + (kt - 8) * 16);
        f4 a1 = *(const f4*)(zr + (kt - 8) * 16 + 4);
        bf8 a = { f2bf(a0[0]), f2bf(a0[1]), f2bf(a0[2]), f2bf(a0[3]),
                  f2bf(a1[0]), f2bf(a1[1]), f2bf(a1[2]), f2bf(a1[3]) };
        #pragma unroll
        for (int nt = 0; nt < 4; ++nt) {
            bf8 b = *(const bf8*)&W[((kt * 4 + nt) * 64 + lane) * 8];
            acc[nt] = __builtin_amdgcn_mfma_f32_32x32x16_bf16(a, b, acc[nt], 0, 0, 0);
        }
    }

    // Store: C layout (m74/m101): col = lane&31, row = (reg&3)+8*(reg>>2)+4*hi.
    // Each inst: lanes 0-31 -> 128B dense, lanes 32-63 -> 128B dense (row+4).
    float* ob = out + R * 128;
    #pragma unroll
    for (int reg = 0; reg < 16; ++reg) {
        const int rowA = (reg & 3) + 8 * (reg >> 2) + 4 * hi;
        #pragma unroll
        for (int nt = 0; nt < 4; ++nt)
            ob[rowA * 128 + nt * 32 + lo] = acc[nt][reg];
    }
}

extern "C" void kernel_launch(void* const* d_in, const int* in_sizes, int n_in,
                              void* d_out, int out_size, void* d_ws, size_t ws_size,
                              hipStream_t stream) {
    const float* x  = (const float*)d_in[0];
    const float* z  = (const float*)d_in[1];
    const float* Uw = (const float*)d_in[2];
    const float* Ub = (const float*)d_in[3];
    const float* Aw = (const float*)d_in[4];
    const float* dv = (const float*)d_in[5];
    float* out = (float*)d_out;
    short* pre = (short*)d_ws;            // 64 KB prepacked weights

    const int B       = in_sizes[0] / 128;   // 262144
    const int nblocks = B / 256;             // 8 waves x 32 rows per block

    nemon_prep<<<1, 256, 0, stream>>>(Uw, Aw, dv, pre);
    nemon_main<<<nblocks, 512, 0, stream>>>(x, z, Ub, pre, out);
}